// Round 6
// baseline (507.587 us; speedup 1.0000x reference)
//
#include <hip/hip_runtime.h>
#include <math.h>

typedef unsigned short u16;
typedef __attribute__((ext_vector_type(8))) _Float16 half8;
typedef __attribute__((ext_vector_type(4))) float f32x4;

#define NS 8192
#define MS 1024
#define CCH 512
#define CI 256
#define O3 768

// ---- fp16 helpers (bit-level storage as u16) ----
__device__ __forceinline__ float h2f(u16 u) {
    _Float16 h; *(u16*)&h = u; return (float)h;
}
__device__ __forceinline__ u16 f2h(float f) {
    _Float16 h = (_Float16)f; return *(u16*)&h;
}

// async global->LDS 16B
__device__ __forceinline__ void gld16(u16* lds, const u16* g) {
    __builtin_amdgcn_global_load_lds((const __attribute__((address_space(1))) void*)g,
                                     (__attribute__((address_space(3))) void*)lds,
                                     16, 0, 0);
}

// ---------------------------------------------------------------------------
// prep: concat+convert weights to fp16
__global__ void prep_w(const float* __restrict__ tw, const float* __restrict__ tb,
                       const float* __restrict__ pw, const float* __restrict__ pb,
                       const float* __restrict__ gw, const float* __restrict__ gb,
                       const float* __restrict__ wzw,
                       u16* __restrict__ W3b, float* __restrict__ b3, u16* __restrict__ wzb) {
    int i = blockIdx.x * 256 + threadIdx.x;
    if (i < O3 * CCH) {
        int o = i >> 9, c = i & 511;
        float v = (o < 256) ? tw[o * 512 + c] : (o < 512) ? pw[(o - 256) * 512 + c]
                                              : gw[(o - 512) * 512 + c];
        W3b[i] = f2h(v);
    } else {
        int j = i - O3 * CCH;
        if (j < CCH * CI) wzb[j] = f2h(wzw[j]);
    }
    if (i < O3) b3[i] = (i < 256) ? tb[i] : (i < 512) ? pb[i - 256] : gb[i - 512];
}

// ---------------------------------------------------------------------------
// transpose x[b][c][n] fp32 -> xt[b][n][c] fp16   (tile 64c x 128n)
__global__ __launch_bounds__(256) void transpose_x(const float* __restrict__ x,
                                                   u16* __restrict__ xt) {
    __shared__ float tile[64][129];
    int b = blockIdx.z;
    int n0 = blockIdx.x * 128, c0 = blockIdx.y * 64;
    const float* xb = x + ((size_t)b * CCH + c0) * NS + n0;
    int t = threadIdx.x;
    #pragma unroll
    for (int i = 0; i < 32; ++i) {
        int idx = t + i * 256;
        int c = idx >> 7, n = idx & 127;
        tile[c][n] = xb[(size_t)c * NS + n];
    }
    __syncthreads();
    u16* xo = xt + ((size_t)b * NS + n0) * CCH + c0;
    #pragma unroll
    for (int i = 0; i < 16; ++i) {
        int idx = t + i * 256;
        int cp = idx & 31, n = idx >> 5;
        unsigned lo = f2h(tile[2 * cp][n]);
        unsigned hi = f2h(tile[2 * cp + 1][n]);
        *(unsigned*)(xo + (size_t)n * CCH + 2 * cp) = lo | (hi << 16);
    }
}

// ---------------------------------------------------------------------------
// NT GEMM (fp16, MFMA): C[M][N] = A[M][K] * B[N][K]^T (+bias), C fp16
// XCD-chunked block swizzle (grid size must be divisible by 8).
// BIAS_MODE: 0 none, 1 by-row (fp32), 2 by-col (fp32)
template<int BIAS_MODE>
__global__ __launch_bounds__(256) void gemm_nt_f16(
        const u16* __restrict__ A, const u16* __restrict__ Bm,
        u16* __restrict__ C, const float* __restrict__ bias,
        int lda, int ldb, int ldc, int Ksize,
        size_t strideA, size_t strideB, size_t strideC) {
    __shared__ u16 As[128 * 64];
    __shared__ u16 Bs[128 * 64];
    const int t = threadIdx.x;
    const int l = t & 63, w = t >> 6;
    const int wr = w >> 1, wc = w & 1;
    const int fr = l & 15, fq = l >> 4;

    // XCD-chunked swizzle: XCD k owns a contiguous span of original order
    const int nx = gridDim.x, ny = gridDim.y;
    int bid = blockIdx.x + nx * (blockIdx.y + ny * blockIdx.z);
    int cpx = (nx * ny * (int)gridDim.z) >> 3;
    int W = (bid & 7) * cpx + (bid >> 3);
    int bx = W % nx, rem = W / nx;
    int by = rem % ny, bz = rem / ny;

    const u16* gA = A + (size_t)bz * strideA + (size_t)(by * 128) * lda;
    const u16* gB = Bm + (size_t)bz * strideB + (size_t)(bx * 128) * ldb;

    f32x4 acc[4][4];
    #pragma unroll
    for (int m = 0; m < 4; ++m)
        #pragma unroll
        for (int n = 0; n < 4; ++n) acc[m][n] = (f32x4)0.f;

    for (int k0 = 0; k0 < Ksize; k0 += 64) {
        #pragma unroll
        for (int i = 0; i < 4; ++i) {
            int cd = t + i * 256;
            int row = cd >> 3, k8 = (cd & 7) * 8;
            int lbase = (cd & ~63) * 8;
            gld16(&As[lbase], gA + (size_t)row * lda + k0 + k8);
            gld16(&Bs[lbase], gB + (size_t)row * ldb + k0 + k8);
        }
        __syncthreads();

        half8 fa[4][2], fb[4][2];
        #pragma unroll
        for (int m = 0; m < 4; ++m)
            #pragma unroll
            for (int kk = 0; kk < 2; ++kk) {
                fa[m][kk] = *(const half8*)&As[(wr * 64 + m * 16 + fr) * 64 + kk * 32 + fq * 8];
                fb[m][kk] = *(const half8*)&Bs[(wc * 64 + m * 16 + fr) * 64 + kk * 32 + fq * 8];
            }
        #pragma unroll
        for (int kk = 0; kk < 2; ++kk)
            #pragma unroll
            for (int m = 0; m < 4; ++m)
                #pragma unroll
                for (int n = 0; n < 4; ++n)
                    acc[m][n] = __builtin_amdgcn_mfma_f32_16x16x32_f16(
                        fa[m][kk], fb[n][kk], acc[m][n], 0, 0, 0);
        __syncthreads();
    }

    u16* gC = C + (size_t)bz * strideC;
    const int crow0 = by * 128 + wr * 64;
    const int ccol0 = bx * 128 + wc * 64;
    #pragma unroll
    for (int m = 0; m < 4; ++m) {
        #pragma unroll
        for (int n = 0; n < 4; ++n) {
            int col = ccol0 + n * 16 + fr;
            float cb = (BIAS_MODE == 2) ? bias[col] : 0.f;
            #pragma unroll
            for (int j = 0; j < 4; ++j) {
                int row = crow0 + m * 16 + fq * 4 + j;
                float v = acc[m][n][j] + cb;
                if (BIAS_MODE == 1) v += bias[row];
                gC[(size_t)row * ldc + col] = f2h(v);
            }
        }
    }
}

// ---------------------------------------------------------------------------
// maxpool 2x2x2 from proj_t[b][n][768]: phi cols 256..511 -> kb[b][m][ci],
//                                       g   cols 512..767 -> vg[b][ci][m]
__global__ __launch_bounds__(256) void pool_kernel(const u16* __restrict__ proj,
                                                   u16* __restrict__ kb, u16* __restrict__ vg) {
    int tid = blockIdx.x * 256 + threadIdx.x;
    int b = tid >> 18;
    int m = (tid >> 8) & 1023;
    int ci = tid & 255;
    int tp = m >> 8, hp = (m >> 4) & 15, wp = m & 15;
    const u16* pb = proj + (size_t)b * NS * O3;
    float mk = -1e30f, mv = -1e30f;
    #pragma unroll
    for (int d = 0; d < 8; ++d) {
        int dt = d >> 2, dh = (d >> 1) & 1, dw = d & 1;
        int n = (2 * tp + dt) * 1024 + (2 * hp + dh) * 32 + (2 * wp + dw);
        const u16* r = pb + (size_t)n * O3;
        mk = fmaxf(mk, h2f(r[256 + ci]));
        mv = fmaxf(mv, h2f(r[512 + ci]));
    }
    kb[((size_t)b * MS + m) * CI + ci] = f2h(mk);
    vg[((size_t)b * CI + ci) * MS + m] = f2h(mv);
}

// ---------------------------------------------------------------------------
// Fused flash attention: Q = proj[b][n][0:256] (stride 768), K = kb[b][m][ci],
// V^T = vg[b][ci][m].  y[b][n][ci] = softmax(QK^T) V.
// 128 q-rows/block, 4 row-stacked waves (32 rows each). m-tiles of 32,
// K/V DOUBLE-buffered; LDS = 2*16 + 2*16 + 8 = 72 KB -> 2 blocks/CU.
__global__ __launch_bounds__(256) void attn_fused(
        const u16* __restrict__ proj, const u16* __restrict__ kb,
        const u16* __restrict__ vg, u16* __restrict__ y) {
    __shared__ u16 Ks[2][32 * 256];     // 2 x 16 KB
    __shared__ u16 Vs[2][256 * 32];     // 2 x 16 KB
    __shared__ u16 Ps[128 * 32];        // 8 KB, XOR-swizzled (chunk ^= row&3)

    // XCD swizzle: each XCD owns one batch -> its K/V (1 MB) stays L2-resident
    int bid0 = blockIdx.x + 64 * blockIdx.y;
    int W = (bid0 & 7) * 64 + (bid0 >> 3);
    const int b = W >> 6;
    const int n0 = (W & 63) * 128;

    const int t = threadIdx.x;
    const int l = t & 63, w = t >> 6;
    const int fr = l & 15, fq = l >> 4;

    const u16* projb = proj + (size_t)b * NS * O3;
    const u16* kbb = kb + (size_t)b * MS * CI;
    const u16* vgb = vg + (size_t)b * CI * MS;

    // Q fragments in registers: rows n0 + w*32 + mf*16 + fr, k = kk*32 + fq*8
    half8 qf[2][8];
    #pragma unroll
    for (int mf = 0; mf < 2; ++mf) {
        const u16* qrow = projb + (size_t)(n0 + w * 32 + mf * 16 + fr) * O3 + fq * 8;
        #pragma unroll
        for (int kk = 0; kk < 8; ++kk)
            qf[mf][kk] = *(const half8*)(qrow + kk * 32);
    }

    f32x4 accO[2][16];
    #pragma unroll
    for (int mf = 0; mf < 2; ++mf)
        #pragma unroll
        for (int nf = 0; nf < 16; ++nf) accO[mf][nf] = (f32x4)0.f;
    float m_run[2][4], l_run[2][4];
    #pragma unroll
    for (int mf = 0; mf < 2; ++mf)
        #pragma unroll
        for (int j = 0; j < 4; ++j) { m_run[mf][j] = -1e30f; l_run[mf][j] = 0.f; }

    // stage K/V tile (32 m-rows) for m0 into buffer `buf`
    // (pre-swizzled global source, linear LDS dest)
    #define STAGE_KV(buf, m0)                                                     \
        {                                                                         \
            _Pragma("unroll")                                                     \
            for (int i = 0; i < 4; ++i) {                                         \
                int c = t + i * 256;                                              \
                int lb = (c & ~63) << 3;                                          \
                int krow = c >> 5, kk8 = c & 31;                                  \
                gld16(&Ks[buf][lb],                                               \
                      kbb + (size_t)((m0) + krow) * CI + ((kk8 ^ (krow & 7)) << 3)); \
                int vrow = c >> 2, vk8 = c & 3;                                   \
                gld16(&Vs[buf][lb],                                               \
                      vgb + (size_t)vrow * MS + (m0) + ((vk8 ^ (vrow & 3)) << 3)); \
            }                                                                     \
        }

    STAGE_KV(0, 0);
    __syncthreads();    // initial stage landed (compiler drains vmcnt at barrier)

    for (int mt = 0; mt < 32; ++mt) {
        const int cur = mt & 1;
        if (mt < 31) STAGE_KV(cur ^ 1, (mt + 1) * 32);

        // ---- QK^T: S-tile 32 q-rows x 32 m-cols per wave ----
        f32x4 accS[2][2];
        #pragma unroll
        for (int mf = 0; mf < 2; ++mf)
            #pragma unroll
            for (int nf = 0; nf < 2; ++nf) accS[mf][nf] = (f32x4)0.f;
        #pragma unroll
        for (int kk = 0; kk < 8; ++kk) {
            half8 fb[2];
            #pragma unroll
            for (int nf = 0; nf < 2; ++nf) {
                int row = nf * 16 + fr;
                fb[nf] = *(const half8*)&Ks[cur][row * 256 + (((kk << 2) | fq) ^ (row & 7)) * 8];
            }
            #pragma unroll
            for (int mf = 0; mf < 2; ++mf)
                #pragma unroll
                for (int nf = 0; nf < 2; ++nf)
                    accS[mf][nf] = __builtin_amdgcn_mfma_f32_16x16x32_f16(
                        qf[mf][kk], fb[nf], accS[mf][nf], 0, 0, 0);
        }

        // ---- online softmax (rows fully in-wave) ----
        float pm[2][4];
        #pragma unroll
        for (int mf = 0; mf < 2; ++mf)
            #pragma unroll
            for (int j = 0; j < 4; ++j)
                pm[mf][j] = fmaxf(accS[mf][0][j], accS[mf][1][j]);
        #pragma unroll
        for (int off = 1; off < 16; off <<= 1)
            #pragma unroll
            for (int mf = 0; mf < 2; ++mf)
                #pragma unroll
                for (int j = 0; j < 4; ++j)
                    pm[mf][j] = fmaxf(pm[mf][j], __shfl_xor(pm[mf][j], off));

        int chg = 0;
        #pragma unroll
        for (int mf = 0; mf < 2; ++mf)
            #pragma unroll
            for (int j = 0; j < 4; ++j) chg |= (pm[mf][j] > m_run[mf][j]);
        if (__any(chg)) {   // exact defer: skip when max unchanged everywhere
            #pragma unroll
            for (int mf = 0; mf < 2; ++mf)
                #pragma unroll
                for (int j = 0; j < 4; ++j) {
                    float mn = fmaxf(m_run[mf][j], pm[mf][j]);
                    float a = __expf(m_run[mf][j] - mn);
                    m_run[mf][j] = mn;
                    l_run[mf][j] *= a;
                    #pragma unroll
                    for (int nf = 0; nf < 16; ++nf) accO[mf][nf][j] *= a;
                }
        }

        // P = exp(S - m), row sums, store P to swizzled Ps (own wave band)
        #pragma unroll
        for (int mf = 0; mf < 2; ++mf)
            #pragma unroll
            for (int j = 0; j < 4; ++j) {
                float ps = 0.f;
                int row = w * 32 + mf * 16 + fq * 4 + j;
                #pragma unroll
                for (int nf = 0; nf < 2; ++nf) {
                    float p = __expf(accS[mf][nf][j] - m_run[mf][j]);
                    ps += p;
                    int col = nf * 16 + fr;
                    Ps[(row << 5) | (col & 7) | ((((col >> 3) ^ row) & 3) << 3)] = f2h(p);
                }
                #pragma unroll
                for (int off = 1; off < 16; off <<= 1) ps += __shfl_xor(ps, off);
                l_run[mf][j] += ps;
            }

        // ---- PV: O += P * V (A from Ps swizzled, same-wave; B from Vs) ----
        half8 fa[2];
        #pragma unroll
        for (int mf = 0; mf < 2; ++mf) {
            int row = w * 32 + mf * 16 + fr;
            fa[mf] = *(const half8*)&Ps[(row << 5) | (((fq ^ row) & 3) << 3)];
        }
        #pragma unroll
        for (int nf = 0; nf < 16; ++nf) {
            int row = nf * 16 + fr;
            half8 fbv = *(const half8*)&Vs[cur][row * 32 + ((fq ^ (row & 3))) * 8];
            #pragma unroll
            for (int mf = 0; mf < 2; ++mf)
                accO[mf][nf] = __builtin_amdgcn_mfma_f32_16x16x32_f16(
                    fa[mf], fbv, accO[mf][nf], 0, 0, 0);
        }
        __syncthreads();   // all waves done with Ks/Vs[cur]; next stage landed
    }

    // epilogue: y[n][ci] = O / l
    u16* yb = y + ((size_t)b * NS + n0 + w * 32) * CI;
    #pragma unroll
    for (int mf = 0; mf < 2; ++mf)
        #pragma unroll
        for (int j = 0; j < 4; ++j) {
            float inv = 1.f / l_run[mf][j];
            int row = mf * 16 + fq * 4 + j;
            #pragma unroll
            for (int nf = 0; nf < 16; ++nf)
                yb[(size_t)row * CI + nf * 16 + fr] = f2h(accO[mf][nf][j] * inv);
        }
    #undef STAGE_KV
}

// ---------------------------------------------------------------------------
// BN stats over z[b][c][n] fp16: one block per channel
__global__ __launch_bounds__(256) void bn_stats(const u16* __restrict__ z,
                                                float* __restrict__ stats) {
    int c = blockIdx.x, t = threadIdx.x;
    float s = 0.f, q = 0.f;
    for (int b = 0; b < 8; ++b) {
        const u16* p = z + ((size_t)b * CCH + c) * NS;
        #pragma unroll
        for (int i = 0; i < 4; ++i) {
            uint4 v = *(const uint4*)(p + (t + i * 256) * 8);
            const u16* u = (const u16*)&v;
            #pragma unroll
            for (int j = 0; j < 8; ++j) { float f = h2f(u[j]); s += f; q += f * f; }
        }
    }
    #pragma unroll
    for (int off = 32; off; off >>= 1) { s += __shfl_xor(s, off); q += __shfl_xor(q, off); }
    __shared__ float rs[4], rq[4];
    int w = t >> 6;
    if ((t & 63) == 0) { rs[w] = s; rq[w] = q; }
    __syncthreads();
    if (t == 0) {
        float S2 = rs[0] + rs[1] + rs[2] + rs[3];
        float Q = rq[0] + rq[1] + rq[2] + rq[3];
        const float inv = 1.f / 65536.f;
        float mean = S2 * inv;
        float var = Q * inv - mean * mean;
        stats[c] = mean;
        stats[CCH + c] = rsqrtf(var + 1e-5f);
    }
}

// ---------------------------------------------------------------------------
// out = (z - mean)*rstd*gamma + beta + x   (8 elems/thread)
__global__ __launch_bounds__(256) void bn_final(const u16* __restrict__ z,
                                                const float* __restrict__ x,
                                                const float* __restrict__ stats,
                                                const float* __restrict__ gamma,
                                                const float* __restrict__ beta,
                                                float* __restrict__ out) {
    size_t i = ((size_t)blockIdx.x * 256 + threadIdx.x) * 8;
    int c = (int)((i >> 13) & 511);
    float g = gamma[c] * stats[CCH + c];
    float sh = beta[c] - stats[c] * g;
    uint4 zv = *(const uint4*)(z + i);
    const u16* u = (const u16*)&zv;
    float4 x0 = *(const float4*)(x + i);
    float4 x1 = *(const float4*)(x + i + 4);
    float4 o0, o1;
    o0.x = h2f(u[0]) * g + sh + x0.x;
    o0.y = h2f(u[1]) * g + sh + x0.y;
    o0.z = h2f(u[2]) * g + sh + x0.z;
    o0.w = h2f(u[3]) * g + sh + x0.w;
    o1.x = h2f(u[4]) * g + sh + x1.x;
    o1.y = h2f(u[5]) * g + sh + x1.y;
    o1.z = h2f(u[6]) * g + sh + x1.z;
    o1.w = h2f(u[7]) * g + sh + x1.w;
    *(float4*)(out + i) = o0;
    *(float4*)(out + i + 4) = o1;
}

// ---------------------------------------------------------------------------
extern "C" void kernel_launch(void* const* d_in, const int* in_sizes, int n_in,
                              void* d_out, int out_size, void* d_ws, size_t ws_size,
                              hipStream_t stream) {
    const float* x       = (const float*)d_in[0];
    const float* theta_w = (const float*)d_in[1];
    const float* theta_b = (const float*)d_in[2];
    const float* phi_w   = (const float*)d_in[3];
    const float* phi_b   = (const float*)d_in[4];
    const float* g_w     = (const float*)d_in[5];
    const float* g_b     = (const float*)d_in[6];
    const float* wz_w    = (const float*)d_in[7];
    const float* wz_b    = (const float*)d_in[8];
    const float* gamma   = (const float*)d_in[9];
    const float* beta    = (const float*)d_in[10];

    char* base = (char*)d_ws;
    u16*   W3b  = (u16*)base;                              // 786432 B
    float* b3   = (float*)(base + 786432);                 // 3072 B
    u16*   wzb  = (u16*)(base + 789504);                   // 262144 B
    float* stats= (float*)(base + 1051648);                // 4096 B
    // region X (67.1 MB): xt, then kb+vg, then z
    u16* xt   = (u16*)(base + 1056768);
    u16* kb   = xt;                                        // after xt dead
    u16* vg   = xt + (size_t)8 * MS * CI;                  // +4 MB
    u16* z    = xt;                                        // after kb/vg dead
    // region P (100.7 MB): proj_t
    u16* proj = (u16*)(base + 1056768 + 67108864);
    // region Y (33.6 MB): y  (must NOT alias proj: attn reads Q from proj)
    u16* y    = (u16*)(base + 1056768 + 67108864 + 100663296);

    // 1) weights
    prep_w<<<2048, 256, 0, stream>>>(theta_w, theta_b, phi_w, phi_b, g_w, g_b,
                                     wz_w, W3b, b3, wzb);
    // 2) x -> xt (fp16, [b][n][c])
    transpose_x<<<dim3(64, 8, 8), 256, 0, stream>>>(x, xt);

    // 3) proj_t[b][n][768] = xt * W3b^T + b3(col)
    gemm_nt_f16<2><<<dim3(6, 64, 8), 256, 0, stream>>>(
        xt, W3b, proj, b3, CCH, CCH, O3, CCH,
        (size_t)NS * CCH, 0, (size_t)NS * O3);

    // 4) pool -> kb[b][m][ci], vg[b][ci][m]
    pool_kernel<<<8192, 256, 0, stream>>>(proj, kb, vg);

    // 5) fused attention -> y[b][n][ci]
    attn_fused<<<dim3(64, 8), 256, 0, stream>>>(proj, kb, vg, y);

    // 6) z[b][c][n] = wzb * y^T + wz_b(row)
    gemm_nt_f16<1><<<dim3(64, 4, 8), 256, 0, stream>>>(
        wzb, y, z, wz_b, CI, CI, NS, CI,
        0, (size_t)NS * CI, (size_t)CCH * NS);

    // 7) BN stats
    bn_stats<<<CCH, 256, 0, stream>>>(z, stats);

    // 8) normalize + residual
    bn_final<<<16384, 256, 0, stream>>>(z, x, stats, gamma, beta, (float*)d_out);
}

// Round 7
// 427.958 us; speedup vs baseline: 1.1861x; 1.1861x over previous
//
#include <hip/hip_runtime.h>
#include <math.h>

typedef unsigned short u16;
typedef __attribute__((ext_vector_type(8))) _Float16 half8;
typedef __attribute__((ext_vector_type(4))) float f32x4;

#define NS 8192
#define MS 1024
#define CCH 512
#define CI 256
#define O3 768

// ---- fp16 helpers (bit-level storage as u16) ----
__device__ __forceinline__ float h2f(u16 u) {
    _Float16 h; *(u16*)&h = u; return (float)h;
}
__device__ __forceinline__ u16 f2h(float f) {
    _Float16 h = (_Float16)f; return *(u16*)&h;
}

// async global->LDS 16B
__device__ __forceinline__ void gld16(u16* lds, const u16* g) {
    __builtin_amdgcn_global_load_lds((const __attribute__((address_space(1))) void*)g,
                                     (__attribute__((address_space(3))) void*)lds,
                                     16, 0, 0);
}

// ---------------------------------------------------------------------------
// prep: concat+convert weights to fp16
__global__ void prep_w(const float* __restrict__ tw, const float* __restrict__ tb,
                       const float* __restrict__ pw, const float* __restrict__ pb,
                       const float* __restrict__ gw, const float* __restrict__ gb,
                       const float* __restrict__ wzw,
                       u16* __restrict__ W3b, float* __restrict__ b3, u16* __restrict__ wzb) {
    int i = blockIdx.x * 256 + threadIdx.x;
    if (i < O3 * CCH) {
        int o = i >> 9, c = i & 511;
        float v = (o < 256) ? tw[o * 512 + c] : (o < 512) ? pw[(o - 256) * 512 + c]
                                              : gw[(o - 512) * 512 + c];
        W3b[i] = f2h(v);
    } else {
        int j = i - O3 * CCH;
        if (j < CCH * CI) wzb[j] = f2h(wzw[j]);
    }
    if (i < O3) b3[i] = (i < 256) ? tb[i] : (i < 512) ? pb[i - 256] : gb[i - 512];
}

// ---------------------------------------------------------------------------
// transpose x[b][c][n] fp32 -> xt[b][n][c] fp16   (tile 64c x 128n)
__global__ __launch_bounds__(256) void transpose_x(const float* __restrict__ x,
                                                   u16* __restrict__ xt) {
    __shared__ float tile[64][129];
    int b = blockIdx.z;
    int n0 = blockIdx.x * 128, c0 = blockIdx.y * 64;
    const float* xb = x + ((size_t)b * CCH + c0) * NS + n0;
    int t = threadIdx.x;
    #pragma unroll
    for (int i = 0; i < 32; ++i) {
        int idx = t + i * 256;
        int c = idx >> 7, n = idx & 127;
        tile[c][n] = xb[(size_t)c * NS + n];
    }
    __syncthreads();
    u16* xo = xt + ((size_t)b * NS + n0) * CCH + c0;
    #pragma unroll
    for (int i = 0; i < 16; ++i) {
        int idx = t + i * 256;
        int cp = idx & 31, n = idx >> 5;
        unsigned lo = f2h(tile[2 * cp][n]);
        unsigned hi = f2h(tile[2 * cp + 1][n]);
        *(unsigned*)(xo + (size_t)n * CCH + 2 * cp) = lo | (hi << 16);
    }
}

// ---------------------------------------------------------------------------
// NT GEMM (fp16, MFMA): C[M][N] = A[M][K] * B[N][K]^T (+bias), C fp16
// XCD-chunked block swizzle (grid size must be divisible by 8).
// BIAS_MODE: 0 none, 1 by-row (fp32), 2 by-col (fp32)
template<int BIAS_MODE>
__global__ __launch_bounds__(256) void gemm_nt_f16(
        const u16* __restrict__ A, const u16* __restrict__ Bm,
        u16* __restrict__ C, const float* __restrict__ bias,
        int lda, int ldb, int ldc, int Ksize,
        size_t strideA, size_t strideB, size_t strideC) {
    __shared__ u16 As[128 * 64];
    __shared__ u16 Bs[128 * 64];
    const int t = threadIdx.x;
    const int l = t & 63, w = t >> 6;
    const int wr = w >> 1, wc = w & 1;
    const int fr = l & 15, fq = l >> 4;

    // XCD-chunked swizzle: XCD k owns a contiguous span of original order
    const int nx = gridDim.x, ny = gridDim.y;
    int bid = blockIdx.x + nx * (blockIdx.y + ny * blockIdx.z);
    int cpx = (nx * ny * (int)gridDim.z) >> 3;
    int W = (bid & 7) * cpx + (bid >> 3);
    int bx = W % nx, rem = W / nx;
    int by = rem % ny, bz = rem / ny;

    const u16* gA = A + (size_t)bz * strideA + (size_t)(by * 128) * lda;
    const u16* gB = Bm + (size_t)bz * strideB + (size_t)(bx * 128) * ldb;

    f32x4 acc[4][4];
    #pragma unroll
    for (int m = 0; m < 4; ++m)
        #pragma unroll
        for (int n = 0; n < 4; ++n) acc[m][n] = (f32x4)0.f;

    for (int k0 = 0; k0 < Ksize; k0 += 64) {
        #pragma unroll
        for (int i = 0; i < 4; ++i) {
            int cd = t + i * 256;
            int row = cd >> 3, k8 = (cd & 7) * 8;
            int lbase = (cd & ~63) * 8;
            gld16(&As[lbase], gA + (size_t)row * lda + k0 + k8);
            gld16(&Bs[lbase], gB + (size_t)row * ldb + k0 + k8);
        }
        __syncthreads();

        half8 fa[4][2], fb[4][2];
        #pragma unroll
        for (int m = 0; m < 4; ++m)
            #pragma unroll
            for (int kk = 0; kk < 2; ++kk) {
                fa[m][kk] = *(const half8*)&As[(wr * 64 + m * 16 + fr) * 64 + kk * 32 + fq * 8];
                fb[m][kk] = *(const half8*)&Bs[(wc * 64 + m * 16 + fr) * 64 + kk * 32 + fq * 8];
            }
        #pragma unroll
        for (int kk = 0; kk < 2; ++kk)
            #pragma unroll
            for (int m = 0; m < 4; ++m)
                #pragma unroll
                for (int n = 0; n < 4; ++n)
                    acc[m][n] = __builtin_amdgcn_mfma_f32_16x16x32_f16(
                        fa[m][kk], fb[n][kk], acc[m][n], 0, 0, 0);
        __syncthreads();
    }

    u16* gC = C + (size_t)bz * strideC;
    const int crow0 = by * 128 + wr * 64;
    const int ccol0 = bx * 128 + wc * 64;
    #pragma unroll
    for (int m = 0; m < 4; ++m) {
        #pragma unroll
        for (int n = 0; n < 4; ++n) {
            int col = ccol0 + n * 16 + fr;
            float cb = (BIAS_MODE == 2) ? bias[col] : 0.f;
            #pragma unroll
            for (int j = 0; j < 4; ++j) {
                int row = crow0 + m * 16 + fq * 4 + j;
                float v = acc[m][n][j] + cb;
                if (BIAS_MODE == 1) v += bias[row];
                gC[(size_t)row * ldc + col] = f2h(v);
            }
        }
    }
}

// ---------------------------------------------------------------------------
// maxpool 2x2x2 from proj_t[b][n][768]: phi cols 256..511 -> kb[b][m][ci],
//                                       g   cols 512..767 -> vg[b][ci][m]
__global__ __launch_bounds__(256) void pool_kernel(const u16* __restrict__ proj,
                                                   u16* __restrict__ kb, u16* __restrict__ vg) {
    int tid = blockIdx.x * 256 + threadIdx.x;
    int b = tid >> 18;
    int m = (tid >> 8) & 1023;
    int ci = tid & 255;
    int tp = m >> 8, hp = (m >> 4) & 15, wp = m & 15;
    const u16* pb = proj + (size_t)b * NS * O3;
    float mk = -1e30f, mv = -1e30f;
    #pragma unroll
    for (int d = 0; d < 8; ++d) {
        int dt = d >> 2, dh = (d >> 1) & 1, dw = d & 1;
        int n = (2 * tp + dt) * 1024 + (2 * hp + dh) * 32 + (2 * wp + dw);
        const u16* r = pb + (size_t)n * O3;
        mk = fmaxf(mk, h2f(r[256 + ci]));
        mv = fmaxf(mv, h2f(r[512 + ci]));
    }
    kb[((size_t)b * MS + m) * CI + ci] = f2h(mk);
    vg[((size_t)b * CI + ci) * MS + m] = f2h(mv);
}

// ---------------------------------------------------------------------------
// Fused flash attention, 8-wave version.
// Q = proj[b][n][0:256] (stride 768), K = kb[b][m][ci], V^T = vg[b][ci][m].
// y[b][n][ci] = softmax(QK^T) V.
// Block: 512 threads = 8 waves, q-tile 256 (wave w owns rows w*32..w*32+31).
// m-tiles of 64, K/V double-buffered (64+64 KB); P via per-wave padded LDS
// band [32][40] (20 KB). Total LDS 148 KB -> 1 block/CU, 2 waves/SIMD.
__global__ __launch_bounds__(512, 2) void attn_fused(
        const u16* __restrict__ proj, const u16* __restrict__ kb,
        const u16* __restrict__ vg, u16* __restrict__ y) {
    __shared__ u16 Ks[2][64 * 256];     // 2 x 32 KB
    __shared__ u16 Vs[2][256 * 64];     // 2 x 32 KB
    __shared__ u16 Ps[8][32][40];       // 20 KB, pad 40 (80B rows, 16B-aligned)

    // XCD swizzle: each XCD owns one batch -> its K/V (1 MB) stays L2-resident
    int bid0 = blockIdx.x + 32 * blockIdx.y;
    int W = (bid0 & 7) * 32 + (bid0 >> 3);
    const int b = W >> 5;
    const int n0 = (W & 31) * 256;

    const int t = threadIdx.x;
    const int l = t & 63, w = t >> 6;
    const int fr = l & 15, fq = l >> 4;

    const u16* projb = proj + (size_t)b * NS * O3;
    const u16* kbb = kb + (size_t)b * MS * CI;
    const u16* vgb = vg + (size_t)b * CI * MS;

    // Q fragments in registers: rows n0 + w*32 + mf*16 + fr, k = kk*32 + fq*8
    half8 qf[2][8];
    #pragma unroll
    for (int mf = 0; mf < 2; ++mf) {
        const u16* qrow = projb + (size_t)(n0 + w * 32 + mf * 16 + fr) * O3 + fq * 8;
        #pragma unroll
        for (int kk = 0; kk < 8; ++kk)
            qf[mf][kk] = *(const half8*)(qrow + kk * 32);
    }

    f32x4 accO[2][16];
    #pragma unroll
    for (int mf = 0; mf < 2; ++mf)
        #pragma unroll
        for (int nf = 0; nf < 16; ++nf) accO[mf][nf] = (f32x4)0.f;
    float m_run[2][4], l_run[2][4];
    #pragma unroll
    for (int mf = 0; mf < 2; ++mf)
        #pragma unroll
        for (int j = 0; j < 4; ++j) { m_run[mf][j] = -1e30f; l_run[mf][j] = 0.f; }

    // stage K/V m-tile (64 rows of K, 64 m-cols of V) into buffer `buf`
    // (pre-swizzled global source, linear LDS dest; 512 threads x 4 chunks)
    #define STAGE_KV(buf, m0)                                                     \
        {                                                                         \
            _Pragma("unroll")                                                     \
            for (int i = 0; i < 4; ++i) {                                         \
                int c = t + i * 512;                                              \
                int lb = (c & ~63) << 3;                                          \
                int krow = c >> 5, kk8 = c & 31;                                  \
                gld16(&Ks[buf][lb],                                               \
                      kbb + (size_t)((m0) + krow) * CI + ((kk8 ^ (krow & 7)) << 3)); \
                int vrow = c >> 3, vk8 = c & 7;                                   \
                gld16(&Vs[buf][lb],                                               \
                      vgb + (size_t)vrow * MS + (m0) + ((vk8 ^ (vrow & 7)) << 3)); \
            }                                                                     \
        }

    STAGE_KV(0, 0);
    __syncthreads();    // initial stage landed (barrier drains vmcnt)

    for (int mt = 0; mt < 16; ++mt) {
        const int cur = mt & 1;
        if (mt < 15) STAGE_KV(cur ^ 1, (mt + 1) * 64);

        // ---- QK^T: S-tile 32 q-rows x 64 m-cols per wave ----
        f32x4 accS[2][4];
        #pragma unroll
        for (int mf = 0; mf < 2; ++mf)
            #pragma unroll
            for (int nf = 0; nf < 4; ++nf) accS[mf][nf] = (f32x4)0.f;
        #pragma unroll
        for (int kk = 0; kk < 8; ++kk) {
            half8 fb[4];
            #pragma unroll
            for (int nf = 0; nf < 4; ++nf) {
                int row = nf * 16 + fr;
                fb[nf] = *(const half8*)&Ks[cur][row * 256 + (((kk << 2) | fq) ^ (row & 7)) * 8];
            }
            #pragma unroll
            for (int mf = 0; mf < 2; ++mf)
                #pragma unroll
                for (int nf = 0; nf < 4; ++nf)
                    accS[mf][nf] = __builtin_amdgcn_mfma_f32_16x16x32_f16(
                        qf[mf][kk], fb[nf], accS[mf][nf], 0, 0, 0);
        }

        // ---- online softmax max + rescale (rows fully in-wave) ----
        float pm[2][4];
        #pragma unroll
        for (int mf = 0; mf < 2; ++mf)
            #pragma unroll
            for (int j = 0; j < 4; ++j)
                pm[mf][j] = fmaxf(fmaxf(accS[mf][0][j], accS[mf][1][j]),
                                  fmaxf(accS[mf][2][j], accS[mf][3][j]));
        #pragma unroll
        for (int off = 1; off < 16; off <<= 1)
            #pragma unroll
            for (int mf = 0; mf < 2; ++mf)
                #pragma unroll
                for (int j = 0; j < 4; ++j)
                    pm[mf][j] = fmaxf(pm[mf][j], __shfl_xor(pm[mf][j], off));

        int chg = 0;
        #pragma unroll
        for (int mf = 0; mf < 2; ++mf)
            #pragma unroll
            for (int j = 0; j < 4; ++j) chg |= (pm[mf][j] > m_run[mf][j]);
        if (__any(chg)) {   // exact defer: skip when max unchanged everywhere
            #pragma unroll
            for (int mf = 0; mf < 2; ++mf)
                #pragma unroll
                for (int j = 0; j < 4; ++j) {
                    float mn = fmaxf(m_run[mf][j], pm[mf][j]);
                    float a = __expf(m_run[mf][j] - mn);
                    m_run[mf][j] = mn;
                    l_run[mf][j] *= a;
                    #pragma unroll
                    for (int nf = 0; nf < 16; ++nf) accO[mf][nf][j] *= a;
                }
        }

        // ---- P-store + PV fused per 32-wide k-half (Ps band is wave-private;
        //      intra-wave WAR/RAW on Ps handled by compiler lgkmcnt) ----
        #pragma unroll
        for (int kkm = 0; kkm < 2; ++kkm) {
            #pragma unroll
            for (int mf = 0; mf < 2; ++mf)
                #pragma unroll
                for (int j = 0; j < 4; ++j) {
                    float ps = 0.f;
                    #pragma unroll
                    for (int nfh = 0; nfh < 2; ++nfh) {
                        float p = __expf(accS[mf][kkm * 2 + nfh][j] - m_run[mf][j]);
                        ps += p;
                        Ps[w][mf * 16 + fq * 4 + j][nfh * 16 + fr] = f2h(p);
                    }
                    #pragma unroll
                    for (int off = 1; off < 16; off <<= 1) ps += __shfl_xor(ps, off);
                    l_run[mf][j] += ps;
                }
            half8 fa[2];
            #pragma unroll
            for (int mf = 0; mf < 2; ++mf)
                fa[mf] = *(const half8*)&Ps[w][mf * 16 + fr][fq * 8];
            #pragma unroll
            for (int nf = 0; nf < 16; ++nf) {
                int row = nf * 16 + fr;
                half8 fbv = *(const half8*)&Vs[cur][row * 64 + (((kkm << 2) | fq) ^ (row & 7)) * 8];
                #pragma unroll
                for (int mf = 0; mf < 2; ++mf)
                    accO[mf][nf] = __builtin_amdgcn_mfma_f32_16x16x32_f16(
                        fa[mf], fbv, accO[mf][nf], 0, 0, 0);
            }
        }
        __syncthreads();   // all waves done with Ks/Vs[cur]; next stage landed
    }

    // epilogue: y[n][ci] = O / l
    u16* yb = y + ((size_t)b * NS + n0 + w * 32) * CI;
    #pragma unroll
    for (int mf = 0; mf < 2; ++mf)
        #pragma unroll
        for (int j = 0; j < 4; ++j) {
            float inv = 1.f / l_run[mf][j];
            int row = mf * 16 + fq * 4 + j;
            #pragma unroll
            for (int nf = 0; nf < 16; ++nf)
                yb[(size_t)row * CI + nf * 16 + fr] = f2h(accO[mf][nf][j] * inv);
        }
    #undef STAGE_KV
}

// ---------------------------------------------------------------------------
// BN stats over z[b][c][n] fp16: one block per channel
__global__ __launch_bounds__(256) void bn_stats(const u16* __restrict__ z,
                                                float* __restrict__ stats) {
    int c = blockIdx.x, t = threadIdx.x;
    float s = 0.f, q = 0.f;
    for (int b = 0; b < 8; ++b) {
        const u16* p = z + ((size_t)b * CCH + c) * NS;
        #pragma unroll
        for (int i = 0; i < 4; ++i) {
            uint4 v = *(const uint4*)(p + (t + i * 256) * 8);
            const u16* u = (const u16*)&v;
            #pragma unroll
            for (int j = 0; j < 8; ++j) { float f = h2f(u[j]); s += f; q += f * f; }
        }
    }
    #pragma unroll
    for (int off = 32; off; off >>= 1) { s += __shfl_xor(s, off); q += __shfl_xor(q, off); }
    __shared__ float rs[4], rq[4];
    int w = t >> 6;
    if ((t & 63) == 0) { rs[w] = s; rq[w] = q; }
    __syncthreads();
    if (t == 0) {
        float S2 = rs[0] + rs[1] + rs[2] + rs[3];
        float Q = rq[0] + rq[1] + rq[2] + rq[3];
        const float inv = 1.f / 65536.f;
        float mean = S2 * inv;
        float var = Q * inv - mean * mean;
        stats[c] = mean;
        stats[CCH + c] = rsqrtf(var + 1e-5f);
    }
}

// ---------------------------------------------------------------------------
// out = (z - mean)*rstd*gamma + beta + x   (8 elems/thread)
__global__ __launch_bounds__(256) void bn_final(const u16* __restrict__ z,
                                                const float* __restrict__ x,
                                                const float* __restrict__ stats,
                                                const float* __restrict__ gamma,
                                                const float* __restrict__ beta,
                                                float* __restrict__ out) {
    size_t i = ((size_t)blockIdx.x * 256 + threadIdx.x) * 8;
    int c = (int)((i >> 13) & 511);
    float g = gamma[c] * stats[CCH + c];
    float sh = beta[c] - stats[c] * g;
    uint4 zv = *(const uint4*)(z + i);
    const u16* u = (const u16*)&zv;
    float4 x0 = *(const float4*)(x + i);
    float4 x1 = *(const float4*)(x + i + 4);
    float4 o0, o1;
    o0.x = h2f(u[0]) * g + sh + x0.x;
    o0.y = h2f(u[1]) * g + sh + x0.y;
    o0.z = h2f(u[2]) * g + sh + x0.z;
    o0.w = h2f(u[3]) * g + sh + x0.w;
    o1.x = h2f(u[4]) * g + sh + x1.x;
    o1.y = h2f(u[5]) * g + sh + x1.y;
    o1.z = h2f(u[6]) * g + sh + x1.z;
    o1.w = h2f(u[7]) * g + sh + x1.w;
    *(float4*)(out + i) = o0;
    *(float4*)(out + i + 4) = o1;
}

// ---------------------------------------------------------------------------
extern "C" void kernel_launch(void* const* d_in, const int* in_sizes, int n_in,
                              void* d_out, int out_size, void* d_ws, size_t ws_size,
                              hipStream_t stream) {
    const float* x       = (const float*)d_in[0];
    const float* theta_w = (const float*)d_in[1];
    const float* theta_b = (const float*)d_in[2];
    const float* phi_w   = (const float*)d_in[3];
    const float* phi_b   = (const float*)d_in[4];
    const float* g_w     = (const float*)d_in[5];
    const float* g_b     = (const float*)d_in[6];
    const float* wz_w    = (const float*)d_in[7];
    const float* wz_b    = (const float*)d_in[8];
    const float* gamma   = (const float*)d_in[9];
    const float* beta    = (const float*)d_in[10];

    char* base = (char*)d_ws;
    u16*   W3b  = (u16*)base;                              // 786432 B
    float* b3   = (float*)(base + 786432);                 // 3072 B
    u16*   wzb  = (u16*)(base + 789504);                   // 262144 B
    float* stats= (float*)(base + 1051648);                // 4096 B
    // region X (67.1 MB): xt, then kb+vg, then z
    u16* xt   = (u16*)(base + 1056768);
    u16* kb   = xt;                                        // after xt dead
    u16* vg   = xt + (size_t)8 * MS * CI;                  // +4 MB
    u16* z    = xt;                                        // after kb/vg dead
    // region P (100.7 MB): proj_t
    u16* proj = (u16*)(base + 1056768 + 67108864);
    // region Y (33.6 MB): y  (must NOT alias proj: attn reads Q from proj)
    u16* y    = (u16*)(base + 1056768 + 67108864 + 100663296);

    // 1) weights
    prep_w<<<2048, 256, 0, stream>>>(theta_w, theta_b, phi_w, phi_b, g_w, g_b,
                                     wz_w, W3b, b3, wzb);
    // 2) x -> xt (fp16, [b][n][c])
    transpose_x<<<dim3(64, 8, 8), 256, 0, stream>>>(x, xt);

    // 3) proj_t[b][n][768] = xt * W3b^T + b3(col)
    gemm_nt_f16<2><<<dim3(6, 64, 8), 256, 0, stream>>>(
        xt, W3b, proj, b3, CCH, CCH, O3, CCH,
        (size_t)NS * CCH, 0, (size_t)NS * O3);

    // 4) pool -> kb[b][m][ci], vg[b][ci][m]
    pool_kernel<<<8192, 256, 0, stream>>>(proj, kb, vg);

    // 5) fused attention -> y[b][n][ci]  (512 threads, q-tile 256)
    attn_fused<<<dim3(32, 8), 512, 0, stream>>>(proj, kb, vg, y);

    // 6) z[b][c][n] = wzb * y^T + wz_b(row)
    gemm_nt_f16<1><<<dim3(64, 4, 8), 256, 0, stream>>>(
        wzb, y, z, wz_b, CI, CI, NS, CI,
        0, (size_t)NS * CI, (size_t)CCH * NS);

    // 7) BN stats
    bn_stats<<<CCH, 256, 0, stream>>>(z, stats);

    // 8) normalize + residual
    bn_final<<<16384, 256, 0, stream>>>(z, x, stats, gamma, beta, (float*)d_out);
}

// Round 8
// 388.147 us; speedup vs baseline: 1.3077x; 1.1026x over previous
//
#include <hip/hip_runtime.h>
#include <math.h>

typedef unsigned short u16;
typedef __attribute__((ext_vector_type(8))) _Float16 half8;
typedef __attribute__((ext_vector_type(4))) float f32x4;

#define NS 8192
#define MS 1024
#define CCH 512
#define CI 256
#define O3 768

// ---- fp16 helpers (bit-level storage as u16) ----
__device__ __forceinline__ float h2f(u16 u) {
    _Float16 h; *(u16*)&h = u; return (float)h;
}
__device__ __forceinline__ u16 f2h(float f) {
    _Float16 h = (_Float16)f; return *(u16*)&h;
}

// async global->LDS 16B
__device__ __forceinline__ void gld16(u16* lds, const u16* g) {
    __builtin_amdgcn_global_load_lds((const __attribute__((address_space(1))) void*)g,
                                     (__attribute__((address_space(3))) void*)lds,
                                     16, 0, 0);
}

// ---------------------------------------------------------------------------
// prep: concat+convert weights to fp16
__global__ void prep_w(const float* __restrict__ tw, const float* __restrict__ tb,
                       const float* __restrict__ pw, const float* __restrict__ pb,
                       const float* __restrict__ gw, const float* __restrict__ gb,
                       const float* __restrict__ wzw,
                       u16* __restrict__ W3b, float* __restrict__ b3, u16* __restrict__ wzb) {
    int i = blockIdx.x * 256 + threadIdx.x;
    if (i < O3 * CCH) {
        int o = i >> 9, c = i & 511;
        float v = (o < 256) ? tw[o * 512 + c] : (o < 512) ? pw[(o - 256) * 512 + c]
                                              : gw[(o - 512) * 512 + c];
        W3b[i] = f2h(v);
    } else {
        int j = i - O3 * CCH;
        if (j < CCH * CI) wzb[j] = f2h(wzw[j]);
    }
    if (i < O3) b3[i] = (i < 256) ? tb[i] : (i < 512) ? pb[i - 256] : gb[i - 512];
}

// ---------------------------------------------------------------------------
// transpose x[b][c][n] fp32 -> xt[b][n][c] fp16   (tile 64c x 128n)
__global__ __launch_bounds__(256) void transpose_x(const float* __restrict__ x,
                                                   u16* __restrict__ xt) {
    __shared__ float tile[64][129];
    int b = blockIdx.z;
    int n0 = blockIdx.x * 128, c0 = blockIdx.y * 64;
    const float* xb = x + ((size_t)b * CCH + c0) * NS + n0;
    int t = threadIdx.x;
    #pragma unroll
    for (int i = 0; i < 32; ++i) {
        int idx = t + i * 256;
        int c = idx >> 7, n = idx & 127;
        tile[c][n] = xb[(size_t)c * NS + n];
    }
    __syncthreads();
    u16* xo = xt + ((size_t)b * NS + n0) * CCH + c0;
    #pragma unroll
    for (int i = 0; i < 16; ++i) {
        int idx = t + i * 256;
        int cp = idx & 31, n = idx >> 5;
        unsigned lo = f2h(tile[2 * cp][n]);
        unsigned hi = f2h(tile[2 * cp + 1][n]);
        *(unsigned*)(xo + (size_t)n * CCH + 2 * cp) = lo | (hi << 16);
    }
}

// ---------------------------------------------------------------------------
// NT GEMM (fp16, MFMA): C[M][N] = A[M][K] * B[N][K]^T (+bias), C fp16
// XCD-chunked block swizzle (grid size must be divisible by 8).
// BIAS_MODE: 0 none, 1 by-row (fp32), 2 by-col (fp32)
template<int BIAS_MODE>
__global__ __launch_bounds__(256) void gemm_nt_f16(
        const u16* __restrict__ A, const u16* __restrict__ Bm,
        u16* __restrict__ C, const float* __restrict__ bias,
        int lda, int ldb, int ldc, int Ksize,
        size_t strideA, size_t strideB, size_t strideC) {
    __shared__ u16 As[128 * 64];
    __shared__ u16 Bs[128 * 64];
    const int t = threadIdx.x;
    const int l = t & 63, w = t >> 6;
    const int wr = w >> 1, wc = w & 1;
    const int fr = l & 15, fq = l >> 4;

    // XCD-chunked swizzle: XCD k owns a contiguous span of original order
    const int nx = gridDim.x, ny = gridDim.y;
    int bid = blockIdx.x + nx * (blockIdx.y + ny * blockIdx.z);
    int cpx = (nx * ny * (int)gridDim.z) >> 3;
    int W = (bid & 7) * cpx + (bid >> 3);
    int bx = W % nx, rem = W / nx;
    int by = rem % ny, bz = rem / ny;

    const u16* gA = A + (size_t)bz * strideA + (size_t)(by * 128) * lda;
    const u16* gB = Bm + (size_t)bz * strideB + (size_t)(bx * 128) * ldb;

    f32x4 acc[4][4];
    #pragma unroll
    for (int m = 0; m < 4; ++m)
        #pragma unroll
        for (int n = 0; n < 4; ++n) acc[m][n] = (f32x4)0.f;

    for (int k0 = 0; k0 < Ksize; k0 += 64) {
        #pragma unroll
        for (int i = 0; i < 4; ++i) {
            int cd = t + i * 256;
            int row = cd >> 3, k8 = (cd & 7) * 8;
            int lbase = (cd & ~63) * 8;
            gld16(&As[lbase], gA + (size_t)row * lda + k0 + k8);
            gld16(&Bs[lbase], gB + (size_t)row * ldb + k0 + k8);
        }
        __syncthreads();

        half8 fa[4][2], fb[4][2];
        #pragma unroll
        for (int m = 0; m < 4; ++m)
            #pragma unroll
            for (int kk = 0; kk < 2; ++kk) {
                fa[m][kk] = *(const half8*)&As[(wr * 64 + m * 16 + fr) * 64 + kk * 32 + fq * 8];
                fb[m][kk] = *(const half8*)&Bs[(wc * 64 + m * 16 + fr) * 64 + kk * 32 + fq * 8];
            }
        #pragma unroll
        for (int kk = 0; kk < 2; ++kk)
            #pragma unroll
            for (int m = 0; m < 4; ++m)
                #pragma unroll
                for (int n = 0; n < 4; ++n)
                    acc[m][n] = __builtin_amdgcn_mfma_f32_16x16x32_f16(
                        fa[m][kk], fb[n][kk], acc[m][n], 0, 0, 0);
        __syncthreads();
    }

    u16* gC = C + (size_t)bz * strideC;
    const int crow0 = by * 128 + wr * 64;
    const int ccol0 = bx * 128 + wc * 64;
    #pragma unroll
    for (int m = 0; m < 4; ++m) {
        #pragma unroll
        for (int n = 0; n < 4; ++n) {
            int col = ccol0 + n * 16 + fr;
            float cb = (BIAS_MODE == 2) ? bias[col] : 0.f;
            #pragma unroll
            for (int j = 0; j < 4; ++j) {
                int row = crow0 + m * 16 + fq * 4 + j;
                float v = acc[m][n][j] + cb;
                if (BIAS_MODE == 1) v += bias[row];
                gC[(size_t)row * ldc + col] = f2h(v);
            }
        }
    }
}

// ---------------------------------------------------------------------------
// maxpool 2x2x2 from proj_t[b][n][768]: phi cols 256..511 -> kb[b][m][ci],
//                                       g   cols 512..767 -> vg[b][ci][m]
__global__ __launch_bounds__(256) void pool_kernel(const u16* __restrict__ proj,
                                                   u16* __restrict__ kb, u16* __restrict__ vg) {
    int tid = blockIdx.x * 256 + threadIdx.x;
    int b = tid >> 18;
    int m = (tid >> 8) & 1023;
    int ci = tid & 255;
    int tp = m >> 8, hp = (m >> 4) & 15, wp = m & 15;
    const u16* pb = proj + (size_t)b * NS * O3;
    float mk = -1e30f, mv = -1e30f;
    #pragma unroll
    for (int d = 0; d < 8; ++d) {
        int dt = d >> 2, dh = (d >> 1) & 1, dw = d & 1;
        int n = (2 * tp + dt) * 1024 + (2 * hp + dh) * 32 + (2 * wp + dw);
        const u16* r = pb + (size_t)n * O3;
        mk = fmaxf(mk, h2f(r[256 + ci]));
        mv = fmaxf(mv, h2f(r[512 + ci]));
    }
    kb[((size_t)b * MS + m) * CI + ci] = f2h(mk);
    vg[((size_t)b * CI + ci) * MS + m] = f2h(mv);
}

// ---------------------------------------------------------------------------
// Fused flash attention, 8-wave / 16-rows-per-wave / counted-vmcnt version.
// Q = proj[b][n][0:256] (stride 768), K = kb[b][m][ci], V^T = vg[b][ci][m].
// y[b][n][ci] = softmax(QK^T) V.
// Block: 512 threads = 8 waves, q-tile 128 (wave w owns rows w*16..w*16+15).
// m-tiles of 64, K/V double-buffered (128 KB); P per-wave [16][40] (10 KB).
// Per-thread regs ~170 -> no spill, 2 waves/SIMD. Counted s_waitcnt vmcnt(8)
// + raw s_barrier: next tile's 8 global_load_lds stay in flight across the
// barrier (no drain), so stage latency hides under the previous compute.
__global__ __launch_bounds__(512, 2) void attn_fused(
        const u16* __restrict__ proj, const u16* __restrict__ kb,
        const u16* __restrict__ vg, u16* __restrict__ y) {
    __shared__ u16 Ks[2][64 * 256];     // 2 x 32 KB
    __shared__ u16 Vs[2][256 * 64];     // 2 x 32 KB
    __shared__ u16 Ps[8][16][40];       // 10 KB, pad 40 (80B rows, 16B-aligned)

    // XCD swizzle: each XCD owns one batch -> its K/V (1 MB) stays L2-resident
    int bid0 = blockIdx.x + 64 * blockIdx.y;
    int W = (bid0 & 7) * 64 + (bid0 >> 3);
    const int b = W >> 6;
    const int n0 = (W & 63) * 128;

    const int t = threadIdx.x;
    const int l = t & 63, w = t >> 6;
    const int fr = l & 15, fq = l >> 4;

    const u16* projb = proj + (size_t)b * NS * O3;
    const u16* kbb = kb + (size_t)b * MS * CI;
    const u16* vgb = vg + (size_t)b * CI * MS;

    // Q fragments in registers: row n0 + w*16 + fr, k = kk*32 + fq*8
    half8 qf[8];
    {
        const u16* qrow = projb + (size_t)(n0 + w * 16 + fr) * O3 + fq * 8;
        #pragma unroll
        for (int kk = 0; kk < 8; ++kk)
            qf[kk] = *(const half8*)(qrow + kk * 32);
    }

    f32x4 accO[16];
    #pragma unroll
    for (int nf = 0; nf < 16; ++nf) accO[nf] = (f32x4)0.f;
    float m_run[4], l_run[4];
    #pragma unroll
    for (int j = 0; j < 4; ++j) { m_run[j] = -1e30f; l_run[j] = 0.f; }

    // stage K/V m-tile (64 rows) into buffer `buf`
    // (pre-swizzled global source, linear LDS dest; 512 threads x 4 chunks each)
    #define STAGE_KV(buf, m0)                                                     \
        {                                                                         \
            _Pragma("unroll")                                                     \
            for (int i = 0; i < 4; ++i) {                                         \
                int c = t + i * 512;                                              \
                int lb = (c & ~63) << 3;                                          \
                int krow = c >> 5, kk8 = c & 31;                                  \
                gld16(&Ks[buf][lb],                                               \
                      kbb + (size_t)((m0) + krow) * CI + ((kk8 ^ (krow & 7)) << 3)); \
                int vrow = c >> 3, vk8 = c & 7;                                   \
                gld16(&Vs[buf][lb],                                               \
                      vgb + (size_t)vrow * MS + (m0) + ((vk8 ^ (vrow & 7)) << 3)); \
            }                                                                     \
        }

    STAGE_KV(0, 0);      // 8 loads/thread (tile 0)
    STAGE_KV(1, 64);     // 8 more (tile 1) -> 16 outstanding

    for (int mt = 0; mt < 16; ++mt) {
        const int cur = mt & 1;
        // counted wait: tile mt's 8 loads landed; tile mt+1's 8 may stay in flight
        if (mt == 15) asm volatile("s_waitcnt vmcnt(0)" ::: "memory");
        else          asm volatile("s_waitcnt vmcnt(8)" ::: "memory");
        __builtin_amdgcn_sched_barrier(0);
        __builtin_amdgcn_s_barrier();      // raw barrier: no vmcnt drain

        // ---- QK^T: S-tile 16 q-rows x 64 m-cols per wave ----
        f32x4 accS[4];
        #pragma unroll
        for (int nf = 0; nf < 4; ++nf) accS[nf] = (f32x4)0.f;
        __builtin_amdgcn_s_setprio(1);
        #pragma unroll
        for (int kk = 0; kk < 8; ++kk) {
            half8 fb[4];
            #pragma unroll
            for (int nf = 0; nf < 4; ++nf) {
                int row = nf * 16 + fr;
                fb[nf] = *(const half8*)&Ks[cur][row * 256 + (((kk << 2) | fq) ^ (row & 7)) * 8];
            }
            #pragma unroll
            for (int nf = 0; nf < 4; ++nf)
                accS[nf] = __builtin_amdgcn_mfma_f32_16x16x32_f16(
                    qf[kk], fb[nf], accS[nf], 0, 0, 0);
        }
        __builtin_amdgcn_s_setprio(0);

        // ---- online softmax (rows fully in-wave) ----
        float pm[4];
        #pragma unroll
        for (int j = 0; j < 4; ++j)
            pm[j] = fmaxf(fmaxf(accS[0][j], accS[1][j]),
                          fmaxf(accS[2][j], accS[3][j]));
        #pragma unroll
        for (int off = 1; off < 16; off <<= 1)
            #pragma unroll
            for (int j = 0; j < 4; ++j)
                pm[j] = fmaxf(pm[j], __shfl_xor(pm[j], off));

        int chg = 0;
        #pragma unroll
        for (int j = 0; j < 4; ++j) chg |= (pm[j] > m_run[j]);
        if (__any(chg)) {   // exact defer: skip when max unchanged everywhere
            #pragma unroll
            for (int j = 0; j < 4; ++j) {
                float mn = fmaxf(m_run[j], pm[j]);
                float a = __expf(m_run[j] - mn);
                m_run[j] = mn;
                l_run[j] *= a;
                #pragma unroll
                for (int nf = 0; nf < 16; ++nf) accO[nf][j] *= a;
            }
        }

        // ---- P-store + PV fused per 32-wide k-half (Ps band wave-private) ----
        #pragma unroll
        for (int kkm = 0; kkm < 2; ++kkm) {
            #pragma unroll
            for (int j = 0; j < 4; ++j) {
                float ps = 0.f;
                #pragma unroll
                for (int nfh = 0; nfh < 2; ++nfh) {
                    float p = __expf(accS[kkm * 2 + nfh][j] - m_run[j]);
                    ps += p;
                    Ps[w][fq * 4 + j][nfh * 16 + fr] = f2h(p);
                }
                #pragma unroll
                for (int off = 1; off < 16; off <<= 1) ps += __shfl_xor(ps, off);
                l_run[j] += ps;
            }
            half8 fa = *(const half8*)&Ps[w][fr][fq * 8];
            __builtin_amdgcn_s_setprio(1);
            #pragma unroll
            for (int nf = 0; nf < 16; ++nf) {
                int row = nf * 16 + fr;
                half8 fbv = *(const half8*)&Vs[cur][row * 64 + (((kkm << 2) | fq) ^ (row & 7)) * 8];
                accO[nf] = __builtin_amdgcn_mfma_f32_16x16x32_f16(
                    fa, fbv, accO[nf], 0, 0, 0);
            }
            __builtin_amdgcn_s_setprio(0);
        }

        __builtin_amdgcn_s_barrier();      // all waves done reading buf[cur]
        if (mt < 14) STAGE_KV(cur, (mt + 2) * 64);
    }

    // epilogue: y[n][ci] = O / l
    u16* yb = y + ((size_t)b * NS + n0 + w * 16) * CI;
    #pragma unroll
    for (int j = 0; j < 4; ++j) {
        float inv = 1.f / l_run[j];
        int row = fq * 4 + j;
        #pragma unroll
        for (int nf = 0; nf < 16; ++nf)
            yb[(size_t)row * CI + nf * 16 + fr] = f2h(accO[nf][j] * inv);
    }
    #undef STAGE_KV
}

// ---------------------------------------------------------------------------
// BN stats over z[b][c][n] fp16: one block per channel
__global__ __launch_bounds__(256) void bn_stats(const u16* __restrict__ z,
                                                float* __restrict__ stats) {
    int c = blockIdx.x, t = threadIdx.x;
    float s = 0.f, q = 0.f;
    for (int b = 0; b < 8; ++b) {
        const u16* p = z + ((size_t)b * CCH + c) * NS;
        #pragma unroll
        for (int i = 0; i < 4; ++i) {
            uint4 v = *(const uint4*)(p + (t + i * 256) * 8);
            const u16* u = (const u16*)&v;
            #pragma unroll
            for (int j = 0; j < 8; ++j) { float f = h2f(u[j]); s += f; q += f * f; }
        }
    }
    #pragma unroll
    for (int off = 32; off; off >>= 1) { s += __shfl_xor(s, off); q += __shfl_xor(q, off); }
    __shared__ float rs[4], rq[4];
    int w = t >> 6;
    if ((t & 63) == 0) { rs[w] = s; rq[w] = q; }
    __syncthreads();
    if (t == 0) {
        float S2 = rs[0] + rs[1] + rs[2] + rs[3];
        float Q = rq[0] + rq[1] + rq[2] + rq[3];
        const float inv = 1.f / 65536.f;
        float mean = S2 * inv;
        float var = Q * inv - mean * mean;
        stats[c] = mean;
        stats[CCH + c] = rsqrtf(var + 1e-5f);
    }
}

// ---------------------------------------------------------------------------
// out = (z - mean)*rstd*gamma + beta + x   (8 elems/thread)
__global__ __launch_bounds__(256) void bn_final(const u16* __restrict__ z,
                                                const float* __restrict__ x,
                                                const float* __restrict__ stats,
                                                const float* __restrict__ gamma,
                                                const float* __restrict__ beta,
                                                float* __restrict__ out) {
    size_t i = ((size_t)blockIdx.x * 256 + threadIdx.x) * 8;
    int c = (int)((i >> 13) & 511);
    float g = gamma[c] * stats[CCH + c];
    float sh = beta[c] - stats[c] * g;
    uint4 zv = *(const uint4*)(z + i);
    const u16* u = (const u16*)&zv;
    float4 x0 = *(const float4*)(x + i);
    float4 x1 = *(const float4*)(x + i + 4);
    float4 o0, o1;
    o0.x = h2f(u[0]) * g + sh + x0.x;
    o0.y = h2f(u[1]) * g + sh + x0.y;
    o0.z = h2f(u[2]) * g + sh + x0.z;
    o0.w = h2f(u[3]) * g + sh + x0.w;
    o1.x = h2f(u[4]) * g + sh + x1.x;
    o1.y = h2f(u[5]) * g + sh + x1.y;
    o1.z = h2f(u[6]) * g + sh + x1.z;
    o1.w = h2f(u[7]) * g + sh + x1.w;
    *(float4*)(out + i) = o0;
    *(float4*)(out + i + 4) = o1;
}

// ---------------------------------------------------------------------------
extern "C" void kernel_launch(void* const* d_in, const int* in_sizes, int n_in,
                              void* d_out, int out_size, void* d_ws, size_t ws_size,
                              hipStream_t stream) {
    const float* x       = (const float*)d_in[0];
    const float* theta_w = (const float*)d_in[1];
    const float* theta_b = (const float*)d_in[2];
    const float* phi_w   = (const float*)d_in[3];
    const float* phi_b   = (const float*)d_in[4];
    const float* g_w     = (const float*)d_in[5];
    const float* g_b     = (const float*)d_in[6];
    const float* wz_w    = (const float*)d_in[7];
    const float* wz_b    = (const float*)d_in[8];
    const float* gamma   = (const float*)d_in[9];
    const float* beta    = (const float*)d_in[10];

    char* base = (char*)d_ws;
    u16*   W3b  = (u16*)base;                              // 786432 B
    float* b3   = (float*)(base + 786432);                 // 3072 B
    u16*   wzb  = (u16*)(base + 789504);                   // 262144 B
    float* stats= (float*)(base + 1051648);                // 4096 B
    // region X (67.1 MB): xt, then kb+vg, then z
    u16* xt   = (u16*)(base + 1056768);
    u16* kb   = xt;                                        // after xt dead
    u16* vg   = xt + (size_t)8 * MS * CI;                  // +4 MB
    u16* z    = xt;                                        // after kb/vg dead
    // region P (100.7 MB): proj_t
    u16* proj = (u16*)(base + 1056768 + 67108864);
    // region Y (33.6 MB): y  (must NOT alias proj: attn reads Q from proj)
    u16* y    = (u16*)(base + 1056768 + 67108864 + 100663296);

    // 1) weights
    prep_w<<<2048, 256, 0, stream>>>(theta_w, theta_b, phi_w, phi_b, g_w, g_b,
                                     wz_w, W3b, b3, wzb);
    // 2) x -> xt (fp16, [b][n][c])
    transpose_x<<<dim3(64, 8, 8), 256, 0, stream>>>(x, xt);

    // 3) proj_t[b][n][768] = xt * W3b^T + b3(col)
    gemm_nt_f16<2><<<dim3(6, 64, 8), 256, 0, stream>>>(
        xt, W3b, proj, b3, CCH, CCH, O3, CCH,
        (size_t)NS * CCH, 0, (size_t)NS * O3);

    // 4) pool -> kb[b][m][ci], vg[b][ci][m]
    pool_kernel<<<8192, 256, 0, stream>>>(proj, kb, vg);

    // 5) fused attention -> y[b][n][ci]  (512 threads, q-tile 128, 16 rows/wave)
    attn_fused<<<dim3(64, 8), 512, 0, stream>>>(proj, kb, vg, y);

    // 6) z[b][c][n] = wzb * y^T + wz_b(row)
    gemm_nt_f16<1><<<dim3(64, 4, 8), 256, 0, stream>>>(
        wzb, y, z, wz_b, CI, CI, NS, CI,
        0, (size_t)NS * CI, (size_t)CCH * NS);

    // 7) BN stats
    bn_stats<<<CCH, 256, 0, stream>>>(z, stats);

    // 8) normalize + residual
    bn_final<<<16384, 256, 0, stream>>>(z, x, stats, gamma, beta, (float*)d_out);
}